// Round 11
// baseline (104.432 us; speedup 1.0000x reference)
//
#include <hip/hip_runtime.h>
#include <hip/hip_bf16.h>
#include <stdint.h>

typedef float f32x4 __attribute__((ext_vector_type(4)));
typedef short s16x8 __attribute__((ext_vector_type(8)));
typedef unsigned short u16;
typedef uint8_t u8;

#define LOG2E 1.44269504088896340736f
#define FP8MAX 448.0f   // OCP e4m3fn max normal

#if __has_builtin(__builtin_amdgcn_exp2f)
#define EXP2F __builtin_amdgcn_exp2f
#else
#define EXP2F exp2f
#endif

__device__ __forceinline__ u16 f2bf(float f) {
    union { float f; uint32_t u; } v; v.f = f;
    uint32_t r = v.u + 0x7FFFu + ((v.u >> 16) & 1u);
    return (u16)(r >> 16);
}
__device__ __forceinline__ uint32_t cvt2bf(float lo, float hi) {
    __hip_bfloat162 h = __float22bfloat162_rn(float2{lo, hi});
    union { __hip_bfloat162 h; uint32_t u; } v; v.h = h; return v.u;
}
__device__ __forceinline__ float bflo2f(uint32_t u) {
    union { uint32_t u; float f; } v; v.u = u << 16; return v.f;
}
__device__ __forceinline__ float bfhi2f(uint32_t u) {
    union { uint32_t u; float f; } v; v.u = u & 0xffff0000u; return v.f;
}
// pack 4 floats -> 4 fp8 e4m3 bytes (2x v_cvt_pk_fp8_f32)
__device__ __forceinline__ uint32_t cvt4fp8(float a, float b, float c, float d) {
    int w = __builtin_amdgcn_cvt_pk_fp8_f32(a, b, 0, false);   // bytes 0,1
    w     = __builtin_amdgcn_cvt_pk_fp8_f32(c, d, w, true);    // bytes 2,3
    return (uint32_t)w;
}
// 16-B LDS deposit as two b64 writes (keeps 8-B alignment req with 72-B rows)
__device__ __forceinline__ void ds_write16(u8* d, uint4 v) {
    uint2 lo; lo.x = v.x; lo.y = v.y;
    uint2 hi; hi.x = v.z; hi.y = v.w;
    *(uint2*)(d)     = lo;
    *(uint2*)(d + 8) = hi;
}
// Workgroup barrier WITHOUT the vmcnt(0) drain __syncthreads would emit.
// Each wave drains its OWN LDS ops (lgkmcnt(0)) before arriving, which is
// exactly what cross-wave LDS visibility needs; in-flight global prefetches
// (K, V-stage) keep flying across the barrier.
__device__ __forceinline__ void lds_barrier() {
    asm volatile("s_waitcnt lgkmcnt(0)\n\ts_barrier" ::: "memory");
}

// ---------------------------------------------------------------------------
// Kernel 1: QKV projection. QT/KT bf16, V fp8 e4m3 [C][HW]. Unchanged
// (measured ~12us; fixed harness overhead C ~66us is the ws re-poison fill).
// ---------------------------------------------------------------------------
__global__ __launch_bounds__(256) void qkv_kernel(
    const float* __restrict__ x,
    const float* __restrict__ Wq, const float* __restrict__ bq,
    const float* __restrict__ Wk, const float* __restrict__ bk,
    const float* __restrict__ Wv, const float* __restrict__ bv,
    u16* __restrict__ QT, u16* __restrict__ KT, u8* __restrict__ Vg)
{
    const int tid  = threadIdx.x;
    const int lane = tid & 63;
    const int wave = tid >> 6;
    const int blk  = blockIdx.x;          // 1024 blocks
    const int b    = blk >> 8;            // batch
    const int sub  = blk & 255;
    const int jt   = sub >> 2;            // 64 j-tiles
    const int cg   = sub & 3;             // 4 channel groups of 16
    const int j    = (jt << 6) + lane;

    const float* xb = x + (size_t)b * 64 * 4096 + j;
    float xv[64];
#pragma unroll
    for (int c = 0; c < 64; ++c) xv[c] = xb[(size_t)c * 4096];

#pragma unroll
    for (int co = 0; co < 4; ++co) {
        const int row = __builtin_amdgcn_readfirstlane(cg * 16 + wave * 4 + co);
        const float* wrow = Wv + row * 64;
        float acc = bv[row];
#pragma unroll
        for (int cin = 0; cin < 64; ++cin) acc += wrow[cin] * xv[cin];
        acc = fminf(fmaxf(acc, -FP8MAX), FP8MAX);
        Vg[((size_t)(b * 64 + row)) * 4096 + j] =
            (u8)(__builtin_amdgcn_cvt_pk_fp8_f32(acc, acc, 0, false) & 0xff);
    }

    if (cg == 0) {
        if (wave == 0) {
            union { u16 u[8]; uint4 v; } q;
#pragma unroll
            for (int d = 0; d < 8; ++d) {
                const float* wrow = Wq + d * 64;
                float acc = bq[d];
#pragma unroll
                for (int cin = 0; cin < 64; ++cin) acc += wrow[cin] * xv[cin];
                q.u[d] = f2bf(acc * LOG2E);
            }
            *(uint4*)(QT + ((size_t)b * 4096 + j) * 8) = q.v;
        } else if (wave == 1) {
            union { u16 u[8]; uint4 v; } k;
#pragma unroll
            for (int d = 0; d < 8; ++d) {
                const float* wrow = Wk + d * 64;
                float acc = bk[d];
#pragma unroll
                for (int cin = 0; cin < 64; ++cin) acc += wrow[cin] * xv[cin];
                k.u[d] = f2bf(acc);
            }
            *(uint4*)(KT + ((size_t)b * 4096 + j) * 8) = k.v;
        }
    }
}

// ---------------------------------------------------------------------------
// Kernel 2: flash attention, fp8 V/P, split-K in-block, LDS-staged V.
// R10 got 71->~26us by killing TA line saturation. Residual model: the
// per-iteration __syncthreads emitted "s_waitcnt vmcnt(0) lgkmcnt(0)" —
// draining the in-flight K(t+1)/V(t+1) prefetches every iteration with all
// 16 waves parked (m97 barrier-drain pattern x16). This round: in-loop
// barrier -> lgkmcnt-only s_barrier (lds_barrier()); correctness per
// deposit-after-barrier / read-before-barrier separation (see R10 comment).
// ---------------------------------------------------------------------------
#define P_STRIDE 72   // BYTES per P row (64 fp8 + 8 pad)
#define VROW 72       // BYTES per V-tile row (64 fp8 + 8 pad; 8 | 72)
#define OXW 65        // u32 elems per packed-Ox row

__global__ __launch_bounds__(1024, 4) void attn_kernel(
    const u16* __restrict__ QT, const u16* __restrict__ KT,
    const u8* __restrict__ Vg, const float* __restrict__ x,
    const float* __restrict__ gamma, float* __restrict__ out)
{
    __shared__ alignas(16) u8 p_lds[16][2][16 * P_STRIDE];  // 36864 B
    __shared__ alignas(16) u8 vbuf[4][2][64 * VROW];        // 36864 B
    __shared__ uint32_t OxP[12][8 * OXW];                   // 24960 B
    __shared__ float    Lx[12 * 16];                        //   768 B ~99.5KB

    const int tid  = threadIdx.x;
    const int lane = tid & 63;
    const int wave = tid >> 6;
    const int col  = lane & 15;
    const int quad = lane >> 4;
    const int qg   = wave & 3;          // query group
    const int sp   = wave >> 2;         // key split
    const int blk  = blockIdx.x;
    const int b    = blk >> 6;
    const int i0   = (blk & 63) << 6;
    const int iw   = i0 + qg * 16;      // this wave's first query

    const u16* KTb = KT + (size_t)b * 4096 * 8;
    const u8*  Vb  = Vg + (size_t)b * 64 * 4096;

    const s16x8 z8 = {0,0,0,0,0,0,0,0};
    const f32x4 zero = {0.f, 0.f, 0.f, 0.f};

    // Q fragment (B operand of S^T = K.Q^T): quad0 holds Q[iw+col][0..7]
    s16x8 aq = z8;
    if (quad == 0)
        aq = *(const s16x8*)(QT + ((size_t)b * 4096 + iw + col) * 8);

    f32x4 o[4];
#pragma unroll
    for (int nt = 0; nt < 4; ++nt) o[nt] = zero;
    float lsum = 0.f;

    u8* plA = &p_lds[wave][0][0];
    u8* plB = &p_lds[wave][1][0];

    // V staging role of this lane: channel row srow, 16-B chunk schk
    const int srow = (qg << 4) + (lane >> 2);
    const int schk = lane & 3;
    const u8* vsrc = Vb + (size_t)srow * 4096 + schk * 16;
    u8* vdst0 = &vbuf[sp][0][srow * VROW + schk * 16];
    u8* vdst1 = &vbuf[sp][1][srow * VROW + schk * 16];

    const int jbeg = sp << 10;

    // ---- prologue: K(0) frags + stage V(0) into vbuf[0] ----
    s16x8 kb[4];
#pragma unroll
    for (int nt = 0; nt < 4; ++nt) {
        s16x8 kn = z8;
        if (quad == 0)
            kn = *(const s16x8*)(KTb + (size_t)(jbeg + nt * 16 + col) * 8);
        kb[nt] = kn;
    }
    ds_write16(vdst0, *(const uint4*)(vsrc + jbeg));

    long long ap0 = 0, ap1 = 0;

#pragma unroll 2
    for (int t = 0; t < 16; ++t) {
        const int j0 = jbeg + (t << 6);
        u8* plw = (t & 1) ? plB : plA;   // P(t) target
        u8* plr = (t & 1) ? plA : plB;   // P(t-1) source

        // 0) stage-load V(t+1) tile quarter (coalesced; consumed post-barrier)
        uint4 vstg;
        if (t < 15) vstg = *(const uint4*)(vsrc + j0 + 64);

        // 1) P(t-1) frag reads
        if (t > 0) {
            ap0 = *(const long long*)(plr + col * P_STRIDE + quad * 8);
            ap1 = *(const long long*)(plr + col * P_STRIDE + 32 + quad * 8);
        }

        // 2) S^T(t): A = K (m=key), B = Q (n=query), bf16 K=32 (8 real dims)
        f32x4 s[4];
#pragma unroll
        for (int nt = 0; nt < 4; ++nt)
            s[nt] = __builtin_amdgcn_mfma_f32_16x16x32_bf16(kb[nt], aq, zero, 0, 0, 0);

        // 2b) prefetch K(t+1)
        if (t < 15) {
#pragma unroll
            for (int nt = 0; nt < 4; ++nt) {
                s16x8 kn = z8;
                if (quad == 0)
                    kn = *(const s16x8*)(KTb + (size_t)(j0 + 64 + nt * 16 + col) * 8);
                kb[nt] = kn;
            }
        }

        // 3) P(t) = min(exp2(S), 448); lsum; pack 4 fp8 -> one ds_write_b32
#pragma unroll
        for (int nt = 0; nt < 4; ++nt) {
            float p0 = fminf(EXP2F(s[nt][0]), FP8MAX);
            float p1 = fminf(EXP2F(s[nt][1]), FP8MAX);
            float p2 = fminf(EXP2F(s[nt][2]), FP8MAX);
            float p3 = fminf(EXP2F(s[nt][3]), FP8MAX);
            lsum += (p0 + p1) + (p2 + p3);
            *(uint32_t*)(plw + col * P_STRIDE + nt * 16 + quad * 4) =
                cvt4fp8(p0, p1, p2, p3);
        }
        // Ordering barrier: forbid hoisting next iteration's ap reads above
        // these stores (distinct TBAA types would otherwise permit it).
        asm volatile("" ::: "memory");

        // 4) V(t-1) frags from LDS tile + PV(t-1)
        if (t > 0) {
            const u8* vt = &vbuf[sp][(t - 1) & 1][0];
#pragma unroll
            for (int nt = 0; nt < 4; ++nt) {
                long long b0 = *(const long long*)(vt + (nt * 16 + col) * VROW + quad * 8);
                long long b1 = *(const long long*)(vt + (nt * 16 + col) * VROW + quad * 8 + 32);
                o[nt] = __builtin_amdgcn_mfma_f32_16x16x32_fp8_fp8(ap0, b0, o[nt], 0, 0, 0);
                o[nt] = __builtin_amdgcn_mfma_f32_16x16x32_fp8_fp8(ap1, b1, o[nt], 0, 0, 0);
            }
        }

        // 5) publish V deposits — lgkmcnt-only barrier (NO vmcnt drain:
        //    K(t+1)/V(t+1) global prefetches keep flying across it)
        lds_barrier();

        // 6) deposit V(t+1) into vbuf[(t+1)&1] (old occupant V(t-1) was last
        //    read pre-barrier this iteration; next barrier publishes it)
        if (t < 15) ds_write16((t & 1) ? vdst0 : vdst1, vstg);
    }

    // ---- epilogue: PV(15): P in plB, V(15) in vbuf[sp][1] ----
    {
        ap0 = *(const long long*)(plB + col * P_STRIDE + quad * 8);
        ap1 = *(const long long*)(plB + col * P_STRIDE + 32 + quad * 8);
        const u8* vt = &vbuf[sp][1][0];
#pragma unroll
        for (int nt = 0; nt < 4; ++nt) {
            long long b0 = *(const long long*)(vt + (nt * 16 + col) * VROW + quad * 8);
            long long b1 = *(const long long*)(vt + (nt * 16 + col) * VROW + quad * 8 + 32);
            o[nt] = __builtin_amdgcn_mfma_f32_16x16x32_fp8_fp8(ap0, b0, o[nt], 0, 0, 0);
            o[nt] = __builtin_amdgcn_mfma_f32_16x16x32_fp8_fp8(ap1, b1, o[nt], 0, 0, 0);
        }
    }

    // ---- reduce lsum across quads: every lane -> l[query=col] ----
    lsum += __shfl_xor(lsum, 16, 64);
    lsum += __shfl_xor(lsum, 32, 64);

    // ---- combine the 4 key-splits in LDS ----
    if (sp > 0) {
        const int slice = (sp - 1) * 4 + qg;
        uint32_t* ox = &OxP[slice][0];
#pragma unroll
        for (int nt = 0; nt < 4; ++nt) {
#pragma unroll
            for (int rp = 0; rp < 2; ++rp)
                ox[(quad * 2 + rp) * OXW + nt * 16 + col] =
                    cvt2bf(o[nt][2 * rp], o[nt][2 * rp + 1]);
        }
        if (quad == 0) Lx[slice * 16 + col] = lsum;
    }
    __syncthreads();   // full barrier: OxP/Lx cross-wave publish (once)
    if (sp == 0) {
        float ltot = lsum;
#pragma unroll
        for (int s = 0; s < 3; ++s)
            ltot += Lx[(s * 4 + qg) * 16 + col];
        float linv[4];
#pragma unroll
        for (int r = 0; r < 4; ++r)
            linv[r] = 1.0f / __shfl(ltot, quad * 4 + r, 16);

#pragma unroll
        for (int s = 0; s < 3; ++s) {
            const uint32_t* ox = &OxP[s * 4 + qg][0];
#pragma unroll
            for (int nt = 0; nt < 4; ++nt) {
#pragma unroll
                for (int rp = 0; rp < 2; ++rp) {
                    uint32_t u = ox[(quad * 2 + rp) * OXW + nt * 16 + col];
                    o[nt][2 * rp]     += bflo2f(u);
                    o[nt][2 * rp + 1] += bfhi2f(u);
                }
            }
        }
        const float g = gamma[0];
#pragma unroll
        for (int nt = 0; nt < 4; ++nt) {
            const int c = nt * 16 + col;
#pragma unroll
            for (int r = 0; r < 4; ++r) {
                const int i = iw + quad * 4 + r;
                const size_t idx = ((size_t)(b * 64 + c)) * 4096 + i;
                out[idx] = g * (o[nt][r] * linv[r]) + x[idx];
            }
        }
    }
}

// ---------------------------------------------------------------------------
extern "C" void kernel_launch(void* const* d_in, const int* in_sizes, int n_in,
                              void* d_out, int out_size, void* d_ws, size_t ws_size,
                              hipStream_t stream)
{
    const float* x     = (const float*)d_in[0];
    const float* Wq    = (const float*)d_in[1];
    const float* bq    = (const float*)d_in[2];
    const float* Wk    = (const float*)d_in[3];
    const float* bk    = (const float*)d_in[4];
    const float* Wv    = (const float*)d_in[5];
    const float* bv    = (const float*)d_in[6];
    const float* gamma = (const float*)d_in[7];

    u16* QT = (u16*)d_ws;                 // [4][4096][8]  bf16
    u16* KT = QT + (size_t)4 * 4096 * 8;  // [4][4096][8]  bf16
    u8*  Vg = (u8*)(KT + (size_t)4 * 4096 * 8);  // [4][64][4096] fp8 e4m3

    qkv_kernel<<<1024, 256, 0, stream>>>(x, Wq, bq, Wk, bk, Wv, bv, QT, KT, Vg);
    attn_kernel<<<256, 1024, 0, stream>>>(QT, KT, Vg, x, gamma, (float*)d_out);
}